// Round 9
// baseline (209.764 us; speedup 1.0000x reference)
//
#include <hip/hip_runtime.h>

typedef __bf16 bf16x8 __attribute__((ext_vector_type(8)));
typedef float f32x4 __attribute__((ext_vector_type(4)));

__device__ inline ushort f2bf(float f) {
    unsigned u = __builtin_bit_cast(unsigned, f);
    unsigned r = (u + 0x7FFFu + ((u >> 16) & 1u)) >> 16;  // RNE
    return (ushort)r;
}
__device__ inline uint4 pack8(const float* f) {
    uint4 r;
    r.x = (unsigned)f2bf(f[0]) | ((unsigned)f2bf(f[1]) << 16);
    r.y = (unsigned)f2bf(f[2]) | ((unsigned)f2bf(f[3]) << 16);
    r.z = (unsigned)f2bf(f[4]) | ((unsigned)f2bf(f[5]) << 16);
    r.w = (unsigned)f2bf(f[6]) | ((unsigned)f2bf(f[7]) << 16);
    return r;
}

#define MFMA_BF16(a, b, c) __builtin_amdgcn_mfma_f32_16x16x32_bf16(a, b, c, 0, 0, 0)
#define GLDS(g, l) __builtin_amdgcn_global_load_lds( \
    (const __attribute__((address_space(1))) void*)(g), \
    (__attribute__((address_space(3))) void*)(l), 16, 0, 0)

// Q pre-scaled by 1/sqrt(64)*log2(e): scores land in exp2 domain.
#define QSCALE 0.18033688011112042f

// Convert fp32 x / qkv_w / proj_w to bf16. 8 elems/thread, 4096x256.
__global__ __launch_bounds__(256) void convert3(
    const float* __restrict__ s0, ushort* __restrict__ d0,
    const float* __restrict__ s1, ushort* __restrict__ d1,
    const float* __restrict__ s2, ushort* __restrict__ d2)
{
    const int i = blockIdx.x * 256 + threadIdx.x;
    const float* s; ushort* d; int off;
    if (i < 524288)      { s = s0; d = d0; off = i; }
    else if (i < 917504) { s = s1; d = d1; off = i - 524288; }
    else                 { s = s2; d = d2; off = i - 917504; }
    const float4* f = (const float4*)s + off * 2;
    float fa[8];
    *(float4*)&fa[0] = f[0];
    *(float4*)&fa[4] = f[1];
    ((uint4*)d)[off] = pack8(fa);
}

// QKV = x @ qkv_w^T + bias. 128x128 tile, BK=64, global_load_lds, XOR-swizzled LDS.
// Q (pre-scaled), K -> [BH,T,64]; V transposed -> Vt [BH,64,T]. All coalesced stores.
__global__ __launch_bounds__(256) void gemm_qkv(
    const ushort* __restrict__ A, const ushort* __restrict__ B,
    const float* __restrict__ bias,
    ushort* __restrict__ outQ, ushort* __restrict__ outK, ushort* __restrict__ outV,
    int N, int K)
{
    __shared__ __align__(16) ushort SMEM[17408];   // staging 16K ushorts; epilogue 128x136
    ushort* As = SMEM;
    ushort* Bs = SMEM + 8192;

    const int tid = threadIdx.x;
    const int w = tid >> 6;
    const int lane = tid & 63;
    const int l15 = lane & 15;
    const int quad = lane >> 4;
    const int m0 = blockIdx.x * 128;
    const int n0 = blockIdx.y * 128;
    const int wr = (w & 1) * 64;
    const int wc = (w >> 1) * 64;

    f32x4 acc[4][4] = {};

    for (int k0 = 0; k0 < K; k0 += 64) {
        __syncthreads();
#pragma unroll
        for (int j = 0; j < 4; j++) {
            const int r0 = w * 32 + j * 8;
            const int row = r0 + (lane >> 3);
            const int gcol = ((lane & 7) ^ (row & 7)) * 8;
            GLDS(A + (size_t)(m0 + row) * K + k0 + gcol, As + r0 * 64);
            GLDS(B + (size_t)(n0 + row) * K + k0 + gcol, Bs + r0 * 64);
        }
        __syncthreads();

        bf16x8 af[4][2], bf[4][2];
#pragma unroll
        for (int i = 0; i < 4; i++)
#pragma unroll
            for (int kk = 0; kk < 2; kk++) {
                const int ra = wr + i * 16 + l15;
                const int rb = wc + i * 16 + l15;
                const int ua = ((kk * 4 + quad) ^ (ra & 7)) * 8;
                const int ub = ((kk * 4 + quad) ^ (rb & 7)) * 8;
                af[i][kk] = *(const bf16x8*)&As[ra * 64 + ua];
                bf[i][kk] = *(const bf16x8*)&Bs[rb * 64 + ub];
            }
#pragma unroll
        for (int kk = 0; kk < 2; kk++)
#pragma unroll
            for (int mi = 0; mi < 4; mi++)
#pragma unroll
                for (int ni = 0; ni < 4; ni++)
                    acc[mi][ni] = MFMA_BF16(af[mi][kk], bf[ni][kk], acc[mi][ni]);
    }

    const int which = n0 >> 10;            // uniform per block: 0=Q 1=K 2=V
    ushort* Ct = SMEM;                     // 128 x 136 ushorts
    __syncthreads();
    if (which == 2) {
        // V: transpose in LDS, then 16B stores contiguous along t
#pragma unroll
        for (int mi = 0; mi < 4; mi++)
#pragma unroll
            for (int ni = 0; ni < 4; ni++)
#pragma unroll
                for (int r = 0; r < 4; r++) {
                    const int m_loc = wr + mi * 16 + quad * 4 + r;
                    const int n_loc = wc + ni * 16 + l15;
                    Ct[n_loc * 136 + m_loc] =
                        f2bf(acc[mi][ni][r] + bias[n0 + n_loc]);
                }
        __syncthreads();
        const int b = m0 >> 11;
#pragma unroll
        for (int i = 0; i < 8; i++) {
            const int vi = tid + i * 256;
            const int n_loc = vi >> 4, mblk = vi & 15;
            const uint4 val = *(const uint4*)&Ct[n_loc * 136 + mblk * 8];
            const int t = (m0 & 2047) + mblk * 8;
            const int c = (n0 + n_loc) & 1023;
            const int h = c >> 6, d = c & 63;
            *(uint4*)&outV[((size_t)(b * 16 + h) * 64 + d) * 2048 + t] = val;
        }
    } else {
        // Q/K: repack [m][n] in LDS, then 16B stores contiguous along d
        const float qs = (which == 0) ? QSCALE : 1.0f;
#pragma unroll
        for (int mi = 0; mi < 4; mi++)
#pragma unroll
            for (int ni = 0; ni < 4; ni++)
#pragma unroll
                for (int r = 0; r < 4; r++) {
                    const int m_loc = wr + mi * 16 + quad * 4 + r;
                    const int n_loc = wc + ni * 16 + l15;
                    Ct[m_loc * 136 + n_loc] =
                        f2bf((acc[mi][ni][r] + bias[n0 + n_loc]) * qs);
                }
        __syncthreads();
        ushort* outP = (which == 0) ? outQ : outK;
        const int hb = (n0 & 1023) >> 6;
        const int b = m0 >> 11;
#pragma unroll
        for (int i = 0; i < 8; i++) {
            const int vi = tid + i * 256;
            const int m_loc = vi >> 4, u = vi & 15;
            const uint4 val = *(const uint4*)&Ct[m_loc * 136 + u * 8];
            const int t = (m0 & 2047) + m_loc;
            const int h = hb + (u >> 3);
            const int d8 = (u & 7) * 8;
            *(uint4*)&outP[((size_t)(b * 16 + h)) * 131072 + (size_t)t * 64 + d8] = val;
        }
    }
}

// proj: out = O @ proj_w^T + bias (fp32 out). 64x128 tile -> 512 blocks (2/CU),
// so resident blocks overlap staging with compute (vs 1/CU at 128x128).
__global__ __launch_bounds__(256) void gemm_proj(
    const ushort* __restrict__ A, const ushort* __restrict__ B,
    const float* __restrict__ bias, float* __restrict__ outD)
{
    const int N = 1024, K = 1024;
    __shared__ __align__(16) ushort SMEM[12288];   // As 64x64 | Bs 128x64 (24 KB)
    ushort* As = SMEM;
    ushort* Bs = SMEM + 4096;

    const int tid = threadIdx.x;
    const int w = tid >> 6;
    const int lane = tid & 63;
    const int l15 = lane & 15;
    const int quad = lane >> 4;
    const int m0 = blockIdx.x * 64;
    const int n0 = blockIdx.y * 128;
    const int wr = (w & 1) * 32;
    const int wc = (w >> 1) * 64;

    f32x4 acc[2][4] = {};

    for (int k0 = 0; k0 < K; k0 += 64) {
        __syncthreads();
#pragma unroll
        for (int j = 0; j < 2; j++) {              // A: 16 rows/wave
            const int r0 = w * 16 + j * 8;
            const int row = r0 + (lane >> 3);
            const int gcol = ((lane & 7) ^ (row & 7)) * 8;
            GLDS(A + (size_t)(m0 + row) * K + k0 + gcol, As + r0 * 64);
        }
#pragma unroll
        for (int j = 0; j < 4; j++) {              // B: 32 rows/wave
            const int r0 = w * 32 + j * 8;
            const int row = r0 + (lane >> 3);
            const int gcol = ((lane & 7) ^ (row & 7)) * 8;
            GLDS(B + (size_t)(n0 + row) * K + k0 + gcol, Bs + r0 * 64);
        }
        __syncthreads();

        bf16x8 af[2][2], bf[4][2];
#pragma unroll
        for (int kk = 0; kk < 2; kk++) {
#pragma unroll
            for (int mi = 0; mi < 2; mi++) {
                const int ra = wr + mi * 16 + l15;
                af[mi][kk] = *(const bf16x8*)&As[ra * 64 + (((kk * 4 + quad) ^ (ra & 7)) * 8)];
            }
#pragma unroll
            for (int ni = 0; ni < 4; ni++) {
                const int rb = wc + ni * 16 + l15;
                bf[ni][kk] = *(const bf16x8*)&Bs[rb * 64 + (((kk * 4 + quad) ^ (rb & 7)) * 8)];
            }
        }
#pragma unroll
        for (int kk = 0; kk < 2; kk++)
#pragma unroll
            for (int mi = 0; mi < 2; mi++)
#pragma unroll
                for (int ni = 0; ni < 4; ni++)
                    acc[mi][ni] = MFMA_BF16(af[mi][kk], bf[ni][kk], acc[mi][ni]);
    }

    // epilogue: fp32, two 64-col chunks through LDS, float4 stores
    float* Cf = (float*)SMEM;                      // 64 x 68 floats (17.4 KB)
#pragma unroll
    for (int cch = 0; cch < 2; cch++) {
        __syncthreads();
        if ((wc >> 6) == cch) {
#pragma unroll
            for (int mi = 0; mi < 2; mi++)
#pragma unroll
                for (int ni = 0; ni < 4; ni++)
#pragma unroll
                    for (int r = 0; r < 4; r++) {
                        const int m_loc = wr + mi * 16 + quad * 4 + r;
                        const int nl = ni * 16 + l15;
                        Cf[m_loc * 68 + nl] = acc[mi][ni][r] + bias[n0 + cch * 64 + nl];
                    }
        }
        __syncthreads();
#pragma unroll
        for (int i = 0; i < 4; i++) {
            const int vi = tid + i * 256;          // 1024 float4
            const int m_loc = vi >> 4, u = vi & 15;
            const float4 val = *(const float4*)&Cf[m_loc * 68 + u * 4];
            *(float4*)&outD[(size_t)(m0 + m_loc) * N + n0 + cch * 64 + u * 4] = val;
        }
    }
}

// Flash attention, 128-row Q tiles (wave = 32 q-rows), static softmax,
// row-sum via MFMA ones-trick. grid (bh=32, slot=16), qt = 15-slot (LPT).
// linear%8 = bh%8 -> one bh per XCD (K/V L2-resident).
__global__ __launch_bounds__(256) void attn3(
    const ushort* __restrict__ Q, const ushort* __restrict__ K,
    const ushort* __restrict__ Vt, ushort* __restrict__ O)
{
    __shared__ __align__(16) ushort KV[2][2][64 * 64];  // [buf][K|V], 32 KB
    __shared__ __align__(16) __bf16 Ps[4][32 * 72];     // 18 KB

    const int bh = blockIdx.x;
    const int qt = 15 - blockIdx.y;
    const int q0 = qt * 128;
    const int tid = threadIdx.x;
    const int w = tid >> 6;
    const int lane = tid & 63;
    const int l15 = lane & 15;
    const int quad = lane >> 4;

    auto stage = [&](int kt, int b) {
        const int t0 = kt * 64;
#pragma unroll
        for (int j = 0; j < 2; j++) {
            const int r0 = w * 16 + j * 8;
            const int row = r0 + (lane >> 3);
            const int gcol = ((lane & 7) ^ (row & 7)) * 8;
            GLDS(K + ((size_t)bh * 2048 + t0 + row) * 64 + gcol, &KV[b][0][r0 * 64]);
            GLDS(Vt + ((size_t)bh * 64 + row) * 2048 + t0 + gcol, &KV[b][1][r0 * 64]);
        }
    };

    bf16x8 qf[2][2];
#pragma unroll
    for (int mi = 0; mi < 2; mi++) {
        const ushort* qb = Q + ((size_t)bh * 2048 + q0 + w * 32 + mi * 16 + l15) * 64;
        qf[mi][0] = *(const bf16x8*)(qb + quad * 8);
        qf[mi][1] = *(const bf16x8*)(qb + 32 + quad * 8);
    }

    bf16x8 ones;
#pragma unroll
    for (int j = 0; j < 8; j++) ones[j] = (__bf16)1.0f;

    f32x4 oacc[2][4] = {};
    f32x4 lacc[2] = {};

    stage(0, 0);
    const int ktmax = 2 * qt + 1;

    for (int kt = 0; kt <= ktmax; kt++) {
        __syncthreads();
        if (kt < ktmax) stage(kt + 1, (kt + 1) & 1);

        const ushort* Ks = &KV[kt & 1][0][0];
        const ushort* Vs = &KV[kt & 1][1][0];
        const int t0 = kt * 64;

        // S = Q K^T (exp2 domain; Q pre-scaled)
        f32x4 sacc[2][4] = {};
#pragma unroll
        for (int cb = 0; cb < 4; cb++) {
            const int rr = cb * 16 + l15;
            bf16x8 b0 = *(const bf16x8*)&Ks[rr * 64 + ((quad ^ (rr & 7)) * 8)];
            bf16x8 b1 = *(const bf16x8*)&Ks[rr * 64 + (((4 + quad) ^ (rr & 7)) * 8)];
#pragma unroll
            for (int mi = 0; mi < 2; mi++) {
                sacc[mi][cb] = MFMA_BF16(qf[mi][0], b0, sacc[mi][cb]);
                sacc[mi][cb] = MFMA_BF16(qf[mi][1], b1, sacc[mi][cb]);
            }
        }

        // P = 2^S -> per-wave LDS in A-layout; mask only near the diagonal
        __bf16* pw = &Ps[w][0];
        __builtin_amdgcn_wave_barrier();
        if (t0 + 63 > q0 + w * 32) {           // wave-uniform
#pragma unroll
            for (int mi = 0; mi < 2; mi++)
#pragma unroll
                for (int cb = 0; cb < 4; cb++)
#pragma unroll
                    for (int r = 0; r < 4; r++) {
                        const int col = t0 + cb * 16 + l15;
                        const int row = q0 + w * 32 + mi * 16 + quad * 4 + r;
                        const float x = (col > row) ? -1e30f : sacc[mi][cb][r];
                        pw[(mi * 16 + quad * 4 + r) * 72 + cb * 16 + l15] =
                            (__bf16)__builtin_exp2f(x);
                    }
        } else {
#pragma unroll
            for (int mi = 0; mi < 2; mi++)
#pragma unroll
                for (int cb = 0; cb < 4; cb++)
#pragma unroll
                    for (int r = 0; r < 4; r++)
                        pw[(mi * 16 + quad * 4 + r) * 72 + cb * 16 + l15] =
                            (__bf16)__builtin_exp2f(sacc[mi][cb][r]);
        }
        __builtin_amdgcn_s_waitcnt(0xC07F);    // lgkmcnt(0)
        __builtin_amdgcn_wave_barrier();

        // O += P @ V ; l += P @ 1
#pragma unroll
        for (int kc = 0; kc < 2; kc++) {
            bf16x8 afr[2];
#pragma unroll
            for (int mi = 0; mi < 2; mi++)
                afr[mi] = *(const bf16x8*)&pw[(mi * 16 + l15) * 72 + kc * 32 + quad * 8];
#pragma unroll
            for (int cb = 0; cb < 4; cb++) {
                const int rr = cb * 16 + l15;
                bf16x8 bfr = *(const bf16x8*)&Vs[rr * 64 + (((kc * 4 + quad) ^ (rr & 7)) * 8)];
#pragma unroll
                for (int mi = 0; mi < 2; mi++)
                    oacc[mi][cb] = MFMA_BF16(afr[mi], bfr, oacc[mi][cb]);
            }
#pragma unroll
            for (int mi = 0; mi < 2; mi++)
                lacc[mi] = MFMA_BF16(afr[mi], ones, lacc[mi]);
        }
    }

    const int b = bh >> 4, h = bh & 15;
#pragma unroll
    for (int mi = 0; mi < 2; mi++)
#pragma unroll
        for (int r = 0; r < 4; r++) {
            const float inv = 1.0f / lacc[mi][r];
            const int row = q0 + w * 32 + mi * 16 + quad * 4 + r;
#pragma unroll
            for (int cb = 0; cb < 4; cb++) {
                const int col = h * 64 + cb * 16 + l15;
                O[((size_t)b * 2048 + row) * 1024 + col] = f2bf(oacc[mi][cb][r] * inv);
            }
        }
}

extern "C" void kernel_launch(void* const* d_in, const int* in_sizes, int n_in,
                              void* d_out, int out_size, void* d_ws, size_t ws_size,
                              hipStream_t stream) {
    const float* x      = (const float*)d_in[0];
    const float* qkv_w  = (const float*)d_in[1];
    const float* qkv_b  = (const float*)d_in[2];
    const float* proj_w = (const float*)d_in[3];
    const float* proj_b = (const float*)d_in[4];

    ushort* XbOb  = (ushort*)d_ws + 16;  // [4096,1024] bf16; reused for attn O
    ushort* Wqkv  = XbOb + 4194304;
    ushort* Wproj = Wqkv + 3145728;
    ushort* Qb    = Wproj + 1048576;     // [32,2048,64]
    ushort* Kb    = Qb + 4194304;
    ushort* Vt    = Kb + 4194304;        // [32,64,2048]

    convert3<<<4096, 256, 0, stream>>>(x, XbOb, qkv_w, Wqkv, proj_w, Wproj);
    gemm_qkv<<<dim3(32, 24), 256, 0, stream>>>(XbOb, Wqkv, qkv_b,
                                               Qb, Kb, Vt, 3072, 1024);
    attn3<<<dim3(32, 16), 256, 0, stream>>>(Qb, Kb, Vt, XbOb);
    gemm_proj<<<dim3(64, 8), 256, 0, stream>>>(XbOb, Wproj, proj_b, (float*)d_out);
}

// Round 10
// 198.717 us; speedup vs baseline: 1.0556x; 1.0556x over previous
//
#include <hip/hip_runtime.h>

typedef __bf16 bf16x8 __attribute__((ext_vector_type(8)));
typedef float f32x4 __attribute__((ext_vector_type(4)));

__device__ inline ushort f2bf(float f) {
    unsigned u = __builtin_bit_cast(unsigned, f);
    unsigned r = (u + 0x7FFFu + ((u >> 16) & 1u)) >> 16;  // RNE
    return (ushort)r;
}
__device__ inline float bf2f(ushort u) {
    unsigned x = ((unsigned)u) << 16;
    return __builtin_bit_cast(float, x);
}
__device__ inline uint4 pack8(const float* f) {
    uint4 r;
    r.x = (unsigned)f2bf(f[0]) | ((unsigned)f2bf(f[1]) << 16);
    r.y = (unsigned)f2bf(f[2]) | ((unsigned)f2bf(f[3]) << 16);
    r.z = (unsigned)f2bf(f[4]) | ((unsigned)f2bf(f[5]) << 16);
    r.w = (unsigned)f2bf(f[6]) | ((unsigned)f2bf(f[7]) << 16);
    return r;
}

#define MFMA_BF16(a, b, c) __builtin_amdgcn_mfma_f32_16x16x32_bf16(a, b, c, 0, 0, 0)
#define GLDS(g, l) __builtin_amdgcn_global_load_lds( \
    (const __attribute__((address_space(1))) void*)(g), \
    (__attribute__((address_space(3))) void*)(l), 16, 0, 0)

// Q pre-scaled by 1/sqrt(64)*log2(e): scores land in exp2 domain.
#define QSCALE 0.18033688011112042f

// Convert fp32 x / qkv_w / proj_w to bf16. 8 elems/thread, 4096x256.
__global__ __launch_bounds__(256) void convert3(
    const float* __restrict__ s0, ushort* __restrict__ d0,
    const float* __restrict__ s1, ushort* __restrict__ d1,
    const float* __restrict__ s2, ushort* __restrict__ d2)
{
    const int i = blockIdx.x * 256 + threadIdx.x;
    const float* s; ushort* d; int off;
    if (i < 524288)      { s = s0; d = d0; off = i; }
    else if (i < 917504) { s = s1; d = d1; off = i - 524288; }
    else                 { s = s2; d = d2; off = i - 917504; }
    const float4* f = (const float4*)s + off * 2;
    float fa[8];
    *(float4*)&fa[0] = f[0];
    *(float4*)&fa[4] = f[1];
    ((uint4*)d)[off] = pack8(fa);
}

// QKV = x @ qkv_w^T + bias. 128x128 tile, BK=64, global_load_lds, XOR-swizzled LDS.
__global__ __launch_bounds__(256) void gemm_qkv(
    const ushort* __restrict__ A, const ushort* __restrict__ B,
    const float* __restrict__ bias,
    ushort* __restrict__ outQ, ushort* __restrict__ outK, ushort* __restrict__ outV,
    int N, int K)
{
    __shared__ __align__(16) ushort SMEM[17408];
    ushort* As = SMEM;
    ushort* Bs = SMEM + 8192;

    const int tid = threadIdx.x;
    const int w = tid >> 6;
    const int lane = tid & 63;
    const int l15 = lane & 15;
    const int quad = lane >> 4;
    const int m0 = blockIdx.x * 128;
    const int n0 = blockIdx.y * 128;
    const int wr = (w & 1) * 64;
    const int wc = (w >> 1) * 64;

    f32x4 acc[4][4] = {};

    for (int k0 = 0; k0 < K; k0 += 64) {
        __syncthreads();
#pragma unroll
        for (int j = 0; j < 4; j++) {
            const int r0 = w * 32 + j * 8;
            const int row = r0 + (lane >> 3);
            const int gcol = ((lane & 7) ^ (row & 7)) * 8;
            GLDS(A + (size_t)(m0 + row) * K + k0 + gcol, As + r0 * 64);
            GLDS(B + (size_t)(n0 + row) * K + k0 + gcol, Bs + r0 * 64);
        }
        __syncthreads();

        bf16x8 af[4][2], bf[4][2];
#pragma unroll
        for (int i = 0; i < 4; i++)
#pragma unroll
            for (int kk = 0; kk < 2; kk++) {
                const int ra = wr + i * 16 + l15;
                const int rb = wc + i * 16 + l15;
                af[i][kk] = *(const bf16x8*)&As[ra * 64 + (((kk * 4 + quad) ^ (ra & 7)) * 8)];
                bf[i][kk] = *(const bf16x8*)&Bs[rb * 64 + (((kk * 4 + quad) ^ (rb & 7)) * 8)];
            }
#pragma unroll
        for (int kk = 0; kk < 2; kk++)
#pragma unroll
            for (int mi = 0; mi < 4; mi++)
#pragma unroll
                for (int ni = 0; ni < 4; ni++)
                    acc[mi][ni] = MFMA_BF16(af[mi][kk], bf[ni][kk], acc[mi][ni]);
    }

    const int which = n0 >> 10;            // 0=Q 1=K 2=V
    ushort* Ct = SMEM;                     // 128 x 136
    __syncthreads();
    if (which == 2) {
#pragma unroll
        for (int mi = 0; mi < 4; mi++)
#pragma unroll
            for (int ni = 0; ni < 4; ni++)
#pragma unroll
                for (int r = 0; r < 4; r++) {
                    const int m_loc = wr + mi * 16 + quad * 4 + r;
                    const int n_loc = wc + ni * 16 + l15;
                    Ct[n_loc * 136 + m_loc] =
                        f2bf(acc[mi][ni][r] + bias[n0 + n_loc]);
                }
        __syncthreads();
        const int b = m0 >> 11;
#pragma unroll
        for (int i = 0; i < 8; i++) {
            const int vi = tid + i * 256;
            const int n_loc = vi >> 4, mblk = vi & 15;
            const uint4 val = *(const uint4*)&Ct[n_loc * 136 + mblk * 8];
            const int t = (m0 & 2047) + mblk * 8;
            const int c = (n0 + n_loc) & 1023;
            const int h = c >> 6, d = c & 63;
            *(uint4*)&outV[((size_t)(b * 16 + h) * 64 + d) * 2048 + t] = val;
        }
    } else {
        const float qs = (which == 0) ? QSCALE : 1.0f;
#pragma unroll
        for (int mi = 0; mi < 4; mi++)
#pragma unroll
            for (int ni = 0; ni < 4; ni++)
#pragma unroll
                for (int r = 0; r < 4; r++) {
                    const int m_loc = wr + mi * 16 + quad * 4 + r;
                    const int n_loc = wc + ni * 16 + l15;
                    Ct[m_loc * 136 + n_loc] =
                        f2bf((acc[mi][ni][r] + bias[n0 + n_loc]) * qs);
                }
        __syncthreads();
        ushort* outP = (which == 0) ? outQ : outK;
        const int hb = (n0 & 1023) >> 6;
        const int b = m0 >> 11;
#pragma unroll
        for (int i = 0; i < 8; i++) {
            const int vi = tid + i * 256;
            const int m_loc = vi >> 4, u = vi & 15;
            const uint4 val = *(const uint4*)&Ct[m_loc * 136 + u * 8];
            const int t = (m0 & 2047) + m_loc;
            const int h = hb + (u >> 3);
            const int d8 = (u & 7) * 8;
            *(uint4*)&outP[((size_t)(b * 16 + h)) * 131072 + (size_t)t * 64 + d8] = val;
        }
    }
}

// proj: out = O @ proj_w^T + bias (fp32). 64x128 tile -> 512 blocks (2/CU).
__global__ __launch_bounds__(256) void gemm_proj(
    const ushort* __restrict__ A, const ushort* __restrict__ B,
    const float* __restrict__ bias, float* __restrict__ outD)
{
    const int N = 1024, K = 1024;
    __shared__ __align__(16) ushort SMEM[12288];
    ushort* As = SMEM;
    ushort* Bs = SMEM + 4096;

    const int tid = threadIdx.x;
    const int w = tid >> 6;
    const int lane = tid & 63;
    const int l15 = lane & 15;
    const int quad = lane >> 4;
    const int m0 = blockIdx.x * 64;
    const int n0 = blockIdx.y * 128;
    const int wr = (w & 1) * 32;
    const int wc = (w >> 1) * 64;

    f32x4 acc[2][4] = {};

    for (int k0 = 0; k0 < K; k0 += 64) {
        __syncthreads();
#pragma unroll
        for (int j = 0; j < 2; j++) {
            const int r0 = w * 16 + j * 8;
            const int row = r0 + (lane >> 3);
            const int gcol = ((lane & 7) ^ (row & 7)) * 8;
            GLDS(A + (size_t)(m0 + row) * K + k0 + gcol, As + r0 * 64);
        }
#pragma unroll
        for (int j = 0; j < 4; j++) {
            const int r0 = w * 32 + j * 8;
            const int row = r0 + (lane >> 3);
            const int gcol = ((lane & 7) ^ (row & 7)) * 8;
            GLDS(B + (size_t)(n0 + row) * K + k0 + gcol, Bs + r0 * 64);
        }
        __syncthreads();

        bf16x8 af[2][2], bf[4][2];
#pragma unroll
        for (int kk = 0; kk < 2; kk++) {
#pragma unroll
            for (int mi = 0; mi < 2; mi++) {
                const int ra = wr + mi * 16 + l15;
                af[mi][kk] = *(const bf16x8*)&As[ra * 64 + (((kk * 4 + quad) ^ (ra & 7)) * 8)];
            }
#pragma unroll
            for (int ni = 0; ni < 4; ni++) {
                const int rb = wc + ni * 16 + l15;
                bf[ni][kk] = *(const bf16x8*)&Bs[rb * 64 + (((kk * 4 + quad) ^ (rb & 7)) * 8)];
            }
        }
#pragma unroll
        for (int kk = 0; kk < 2; kk++)
#pragma unroll
            for (int mi = 0; mi < 2; mi++)
#pragma unroll
                for (int ni = 0; ni < 4; ni++)
                    acc[mi][ni] = MFMA_BF16(af[mi][kk], bf[ni][kk], acc[mi][ni]);
    }

    float* Cf = (float*)SMEM;                      // 64 x 68 floats
#pragma unroll
    for (int cch = 0; cch < 2; cch++) {
        __syncthreads();
        if ((wc >> 6) == cch) {
#pragma unroll
            for (int mi = 0; mi < 2; mi++)
#pragma unroll
                for (int ni = 0; ni < 4; ni++)
#pragma unroll
                    for (int r = 0; r < 4; r++) {
                        const int m_loc = wr + mi * 16 + quad * 4 + r;
                        const int nl = ni * 16 + l15;
                        Cf[m_loc * 68 + nl] = acc[mi][ni][r] + bias[n0 + cch * 64 + nl];
                    }
        }
        __syncthreads();
#pragma unroll
        for (int i = 0; i < 4; i++) {
            const int vi = tid + i * 256;
            const int m_loc = vi >> 4, u = vi & 15;
            const float4 val = *(const float4*)&Cf[m_loc * 68 + u * 4];
            *(float4*)&outD[(size_t)(m0 + m_loc) * N + n0 + cch * 64 + u * 4] = val;
        }
    }
}

// Split-K flash attention, static softmax (kt tiles are independent pure sums).
// 64-row Q tiles, 4 waves x 16 q-rows. grid (bh=32, y=56):
//   y<48: qt = 31-(y>>1), chunk = y&1 (two kt-chunks, write partials)
//   y>=48: qt = 55-y (qt<8, single chunk, write O directly)
// LDS = 40960 B exactly -> 4 blocks/CU (16 waves). Ps XOR-swizzled (no pad).
__global__ __launch_bounds__(256) void attn_split(
    const ushort* __restrict__ Q, const ushort* __restrict__ K,
    const ushort* __restrict__ Vt, ushort* __restrict__ O,
    ushort* __restrict__ Opart, float* __restrict__ Lpart)
{
    __shared__ __align__(16) ushort KV[2][2][64 * 64];  // 32 KB
    __shared__ __align__(16) __bf16 Ps[4][16 * 64];     // 8 KB, swizzled

    const int bh = blockIdx.x;
    const int y = blockIdx.y;
    int qt, k0, k1, chunk, split;
    if (y < 48) {
        qt = 31 - (y >> 1); chunk = y & 1; split = 1;
        const int n = qt + 1, h = (n + 1) >> 1;
        k0 = chunk ? h : 0; k1 = chunk ? n : h;
    } else {
        qt = 55 - y; chunk = 0; split = 0; k0 = 0; k1 = qt + 1;
    }
    const int q0 = qt * 64;
    const int tid = threadIdx.x;
    const int w = tid >> 6;
    const int lane = tid & 63;
    const int l15 = lane & 15;
    const int quad = lane >> 4;

    auto stage = [&](int kt, int b) {
        const int t0 = kt * 64;
#pragma unroll
        for (int j = 0; j < 2; j++) {
            const int r0 = w * 16 + j * 8;
            const int row = r0 + (lane >> 3);
            const int gcol = ((lane & 7) ^ (row & 7)) * 8;
            GLDS(K + ((size_t)bh * 2048 + t0 + row) * 64 + gcol, &KV[b][0][r0 * 64]);
            GLDS(Vt + ((size_t)bh * 64 + row) * 2048 + t0 + gcol, &KV[b][1][r0 * 64]);
        }
    };

    const ushort* qbase = Q + ((size_t)bh * 2048 + q0 + w * 16 + l15) * 64;
    bf16x8 qf0 = *(const bf16x8*)(qbase + quad * 8);
    bf16x8 qf1 = *(const bf16x8*)(qbase + 32 + quad * 8);

    bf16x8 ones;
#pragma unroll
    for (int j = 0; j < 8; j++) ones[j] = (__bf16)1.0f;

    f32x4 oacc[4] = {};
    f32x4 lacc = {};

    stage(k0, 0);

    for (int kt = k0; kt < k1; kt++) {
        __syncthreads();
        if (kt + 1 < k1) stage(kt + 1, (kt + 1 - k0) & 1);

        const ushort* Ks = &KV[(kt - k0) & 1][0][0];
        const ushort* Vs = &KV[(kt - k0) & 1][1][0];
        const int t0 = kt * 64;

        f32x4 sacc[4] = {};
#pragma unroll
        for (int cb = 0; cb < 4; cb++) {
            const int rr = cb * 16 + l15;
            bf16x8 b0 = *(const bf16x8*)&Ks[rr * 64 + ((quad ^ (rr & 7)) * 8)];
            bf16x8 b1 = *(const bf16x8*)&Ks[rr * 64 + (((4 + quad) ^ (rr & 7)) * 8)];
            sacc[cb] = MFMA_BF16(qf0, b0, sacc[cb]);
            sacc[cb] = MFMA_BF16(qf1, b1, sacc[cb]);
        }

        // P = 2^S -> per-wave swizzled LDS in A-layout
        __bf16* pw = &Ps[w][0];
        __builtin_amdgcn_wave_barrier();
#pragma unroll
        for (int cb = 0; cb < 4; cb++)
#pragma unroll
            for (int r = 0; r < 4; r++) {
                float x = sacc[cb][r];
                if (kt == qt) {
                    const int col = t0 + cb * 16 + l15;
                    const int row = q0 + w * 16 + quad * 4 + r;
                    if (col > row) x = -1e30f;
                }
                const int prow = quad * 4 + r;
                const int unit = cb * 2 + (l15 >> 3);
                pw[prow * 64 + ((unit ^ (prow & 7)) * 8) + (l15 & 7)] =
                    (__bf16)__builtin_exp2f(x);
            }
        __builtin_amdgcn_s_waitcnt(0xC07F);   // lgkmcnt(0)
        __builtin_amdgcn_wave_barrier();

#pragma unroll
        for (int kc = 0; kc < 2; kc++) {
            bf16x8 afr = *(const bf16x8*)&pw[l15 * 64 + (((kc * 4 + quad) ^ (l15 & 7)) * 8)];
#pragma unroll
            for (int cb = 0; cb < 4; cb++) {
                const int rr = cb * 16 + l15;
                bf16x8 bfr = *(const bf16x8*)&Vs[rr * 64 + (((kc * 4 + quad) ^ (rr & 7)) * 8)];
                oacc[cb] = MFMA_BF16(afr, bfr, oacc[cb]);
            }
            lacc = MFMA_BF16(afr, ones, lacc);
        }
    }

    if (!split) {
        const int b = bh >> 4, h = bh & 15;
#pragma unroll
        for (int r = 0; r < 4; r++) {
            const float inv = 1.0f / lacc[r];
            const int row = q0 + w * 16 + quad * 4 + r;
#pragma unroll
            for (int cb = 0; cb < 4; cb++) {
                const int col = h * 64 + cb * 16 + l15;
                O[((size_t)b * 2048 + row) * 1024 + col] = f2bf(oacc[cb][r] * inv);
            }
        }
    } else {
        const size_t slot2 = ((size_t)bh * 24 + (qt - 8)) * 2 + chunk;
        // l partials (all l15 columns identical after ones-MFMA)
        if (l15 == 0) {
#pragma unroll
            for (int r = 0; r < 4; r++)
                Lpart[slot2 * 64 + w * 16 + quad * 4 + r] = lacc[r];
        }
        // O partial: repack via swizzled pw -> coalesced 16B stores
        __bf16* pw = &Ps[w][0];
        __builtin_amdgcn_wave_barrier();
#pragma unroll
        for (int cb = 0; cb < 4; cb++)
#pragma unroll
            for (int r = 0; r < 4; r++) {
                const int prow = quad * 4 + r;
                const int unit = cb * 2 + (l15 >> 3);
                pw[prow * 64 + ((unit ^ (prow & 7)) * 8) + (l15 & 7)] =
                    (__bf16)oacc[cb][r];
            }
        __builtin_amdgcn_s_waitcnt(0xC07F);
        __builtin_amdgcn_wave_barrier();
        const int r = lane >> 2, u = lane & 3;     // row 0..15, 16-col group
        const int p0 = (2 * u) ^ (r & 7), p1 = (2 * u + 1) ^ (r & 7);
        const uint4 a = *(const uint4*)&pw[r * 64 + p0 * 8];
        const uint4 b = *(const uint4*)&pw[r * 64 + p1 * 8];
        ushort* dst = Opart + slot2 * 4096 + (w * 16 + r) * 64 + u * 16;
        *(uint4*)dst = a;
        *(uint4*)(dst + 8) = b;
    }
}

// Combine: O[bh, qt>=8 rows] = (P0 + P1) / (l0 + l1). grid (32, 24).
__global__ __launch_bounds__(256) void attn_combine(
    const ushort* __restrict__ Opart, const float* __restrict__ Lpart,
    ushort* __restrict__ O)
{
    const int bh = blockIdx.x;
    const int qt = 8 + blockIdx.y;
    const int tid = threadIdx.x;
    const int row = tid >> 2;
    const int cg = (tid & 3) * 16;
    const size_t s = ((size_t)bh * 24 + (qt - 8)) * 2;
    const ushort* p0 = Opart + s * 4096 + row * 64 + cg;
    const ushort* p1 = p0 + 4096;
    const float inv = 1.0f / (Lpart[s * 64 + row] + Lpart[(s + 1) * 64 + row]);
    const int b = bh >> 4, h = bh & 15;
    ushort* dst = O + ((size_t)b * 2048 + qt * 64 + row) * 1024 + h * 64 + cg;
    ushort out[16];
#pragma unroll
    for (int v = 0; v < 2; v++) {
        uint4 a = *(const uint4*)(p0 + v * 8);
        uint4 c = *(const uint4*)(p1 + v * 8);
        const ushort* ua = (const ushort*)&a;
        const ushort* uc = (const ushort*)&c;
#pragma unroll
        for (int j = 0; j < 8; j++)
            out[v * 8 + j] = f2bf((bf2f(ua[j]) + bf2f(uc[j])) * inv);
    }
    *(uint4*)dst = *(uint4*)&out[0];
    *(uint4*)(dst + 8) = *(uint4*)&out[8];
}

extern "C" void kernel_launch(void* const* d_in, const int* in_sizes, int n_in,
                              void* d_out, int out_size, void* d_ws, size_t ws_size,
                              hipStream_t stream) {
    const float* x      = (const float*)d_in[0];
    const float* qkv_w  = (const float*)d_in[1];
    const float* qkv_b  = (const float*)d_in[2];
    const float* proj_w = (const float*)d_in[3];
    const float* proj_b = (const float*)d_in[4];

    ushort* XbOb  = (ushort*)d_ws + 16;  // [4096,1024] bf16; reused for attn O
    ushort* Wqkv  = XbOb + 4194304;
    ushort* Wproj = Wqkv + 3145728;
    ushort* Qb    = Wproj + 1048576;     // [32,2048,64]
    ushort* Kb    = Qb + 4194304;
    ushort* Vt    = Kb + 4194304;        // [32,64,2048]
    ushort* Opart = Vt + 4194304;        // [32][24][2][64*64] bf16 = 12.6 MB
    float*  Lpart = (float*)(Opart + 6291456);  // [32][24][2][64] fp32

    convert3<<<4096, 256, 0, stream>>>(x, XbOb, qkv_w, Wqkv, proj_w, Wproj);
    gemm_qkv<<<dim3(32, 24), 256, 0, stream>>>(XbOb, Wqkv, qkv_b,
                                               Qb, Kb, Vt, 3072, 1024);
    attn_split<<<dim3(32, 56), 256, 0, stream>>>(Qb, Kb, Vt, XbOb, Opart, Lpart);
    attn_combine<<<dim3(32, 24), 256, 0, stream>>>(Opart, Lpart, XbOb);
    gemm_proj<<<dim3(64, 8), 256, 0, stream>>>(XbOb, Wproj, proj_b, (float*)d_out);
}